// Round 1
// baseline (47322.198 us; speedup 1.0000x reference)
//
#include <hip/hip_runtime.h>
#include <math.h>

// Problem constants
#define Bb   128
#define Hd   1024
#define BT   64      // batch rows per WG
#define JT   8       // h-columns per WG  -> 32 gate rows per WG
#define RT   32      // 4*JT gate rows
#define KC   64      // K chunk
#define NT   256     // threads per WG
#define NCHUNK 16    // Hd / KC
#define XSs  68      // LDS row stride (KC+4): 16B-aligned, 2-way bank aliasing only
#define SMs  52      // small-segment LDS stride (K<=50)
#define GBs  33      // gates buffer stride

__device__ __forceinline__ float sigm(float x) { return 1.0f / (1.0f + expf(-x)); }

// Generic fused LSTM-cell kernel:
//   gates[b][jg] = bih[jg]+bhh[jg]
//                + sum_k Xbig0[b][k]*Wbig0[jg][k]          (K=1024)
//                + sum_k Xbig1[b][k]*Wbig1[jg][k]          (optional, K=1024)
//                + sum_k cat(Xsm0,Xsm1)[b][k]*Wsmall[jg][k] (optional, K=K0+K1<=50)
// then LSTM elementwise (i,f,g,o), optional dropout mask, optional FC
// (out += h2@Wfc.T via atomics), optional out-slot init to bfc.
__global__ __launch_bounds__(NT) void lstm_cell_kernel(
    const float* __restrict__ Xbig0, const float* __restrict__ Wbig0,
    const float* __restrict__ Xbig1, const float* __restrict__ Wbig1,
    const float* __restrict__ Xsm0p, int K0,
    const float* __restrict__ Xsm1p, int K1,
    const float* __restrict__ Wsmall,
    const float* __restrict__ bih, const float* __restrict__ bhh,
    const float* __restrict__ cprev, float* __restrict__ cnew,
    const float* __restrict__ mask,
    float* __restrict__ hnew,
    const float* __restrict__ Wfc, const float* __restrict__ bfc,
    float* __restrict__ outp, int initOut)
{
    __shared__ float Xs[BT][XSs];
    __shared__ float Ws[RT][XSs];
    __shared__ float gbuf[BT][GBs];
    __shared__ float hbuf[BT][JT];
    __shared__ float Xsm[BT][SMs];
    __shared__ float Wsm[RT][SMs];

    const int tid = threadIdx.x;
    const int j0  = blockIdx.x * JT;   // h-column tile
    const int b0  = blockIdx.y * BT;   // batch half
    const int jp  = tid & 15;          // rows jp, jp+16 of the 32-row W tile
    const int bq  = tid >> 4;          // b = bq + 16*bb, bb in 0..3

    // gate-row mapping: r in [0,32): r = g*8 + j  -> global row g*Hd + j0 + j
    auto GROW = [&](int r) { return ((r >> 3) * Hd + j0 + (r & 7)); };

    float acc[4][2];
    #pragma unroll
    for (int i = 0; i < 4; ++i) { acc[i][0] = 0.f; acc[i][1] = 0.f; }

    // init this step's out slot to bfc (done by cell1/cell0 kernel; cell2 of the
    // same step accumulates afterwards — separate launch, stream-ordered)
    if (initOut && blockIdx.x == 0 && blockIdx.y == 0) {
        for (int i = tid; i < Bb * 3; i += NT) outp[i] = bfc[i % 3];
    }

    // ---- big segments (K = 1024), LDS-chunked with register prefetch ----
    for (int seg = 0; seg < 2; ++seg) {
        const float* __restrict__ Xg = (seg == 0) ? Xbig0 : Xbig1;
        const float* __restrict__ Wg = (seg == 0) ? Wbig0 : Wbig1;
        if (Xg == nullptr) continue;

        float4 xr[4], wr[2];
        // stage chunk 0
        #pragma unroll
        for (int p = 0; p < 4; ++p) {
            int fi = p * NT + tid; int bloc = fi >> 4; int kq = fi & 15;
            xr[p] = *(const float4*)(Xg + (size_t)(b0 + bloc) * Hd + kq * 4);
        }
        #pragma unroll
        for (int p = 0; p < 2; ++p) {
            int fi = p * NT + tid; int r = fi >> 4; int kq = fi & 15;
            wr[p] = *(const float4*)(Wg + (size_t)GROW(r) * Hd + kq * 4);
        }
        #pragma unroll
        for (int p = 0; p < 4; ++p) { int fi = p * NT + tid; *(float4*)&Xs[fi >> 4][(fi & 15) * 4] = xr[p]; }
        #pragma unroll
        for (int p = 0; p < 2; ++p) { int fi = p * NT + tid; *(float4*)&Ws[fi >> 4][(fi & 15) * 4] = wr[p]; }
        __syncthreads();

        for (int kc = 0; kc < NCHUNK; ++kc) {
            const bool more = (kc + 1) < NCHUNK;
            if (more) {  // prefetch next chunk into regs; latency hides under compute
                const int k0n = (kc + 1) * KC;
                #pragma unroll
                for (int p = 0; p < 4; ++p) {
                    int fi = p * NT + tid; int bloc = fi >> 4; int kq = fi & 15;
                    xr[p] = *(const float4*)(Xg + (size_t)(b0 + bloc) * Hd + k0n + kq * 4);
                }
                #pragma unroll
                for (int p = 0; p < 2; ++p) {
                    int fi = p * NT + tid; int r = fi >> 4; int kq = fi & 15;
                    wr[p] = *(const float4*)(Wg + (size_t)GROW(r) * Hd + k0n + kq * 4);
                }
            }
            // compute on current LDS chunk: 4b x 2jg x 4k register tile
            #pragma unroll 4
            for (int kk = 0; kk < KC; kk += 4) {
                float4 w0 = *(const float4*)&Ws[jp][kk];
                float4 w1 = *(const float4*)&Ws[jp + 16][kk];
                #pragma unroll
                for (int bb = 0; bb < 4; ++bb) {
                    float4 xv = *(const float4*)&Xs[bq + 16 * bb][kk];
                    acc[bb][0] += xv.x * w0.x + xv.y * w0.y + xv.z * w0.z + xv.w * w0.w;
                    acc[bb][1] += xv.x * w1.x + xv.y * w1.y + xv.z * w1.z + xv.w * w1.w;
                }
            }
            __syncthreads();
            if (more) {
                #pragma unroll
                for (int p = 0; p < 4; ++p) { int fi = p * NT + tid; *(float4*)&Xs[fi >> 4][(fi & 15) * 4] = xr[p]; }
                #pragma unroll
                for (int p = 0; p < 2; ++p) { int fi = p * NT + tid; *(float4*)&Ws[fi >> 4][(fi & 15) * 4] = wr[p]; }
                __syncthreads();
            }
        }
    }

    // ---- small segment: concat(Xsm0[K0], Xsm1[K1]) @ Wsmall (row stride K0+K1) ----
    if (Wsmall) {
        const int Kt = K0 + K1;
        for (int i = tid; i < BT * Kt; i += NT) {
            int bloc = i / Kt, k = i % Kt;
            Xsm[bloc][k] = (k < K0) ? Xsm0p[(size_t)(b0 + bloc) * K0 + k]
                                    : Xsm1p[(size_t)(b0 + bloc) * K1 + (k - K0)];
        }
        for (int i = tid; i < RT * Kt; i += NT) {
            int r = i / Kt, k = i % Kt;
            Wsm[r][k] = Wsmall[(size_t)GROW(r) * Kt + k];
        }
        __syncthreads();
        for (int k = 0; k < Kt; ++k) {
            float w0 = Wsm[jp][k], w1 = Wsm[jp + 16][k];
            #pragma unroll
            for (int bb = 0; bb < 4; ++bb) {
                float xv = Xsm[bq + 16 * bb][k];
                acc[bb][0] += xv * w0;
                acc[bb][1] += xv * w1;
            }
        }
    }

    // ---- gates -> LDS so each (b,j) owner sees all four gates ----
    __syncthreads();
    #pragma unroll
    for (int bb = 0; bb < 4; ++bb) {
        gbuf[bq + 16 * bb][jp]      = acc[bb][0];
        gbuf[bq + 16 * bb][jp + 16] = acc[bb][1];
    }
    __syncthreads();

    // ---- LSTM elementwise: 64b x 8j = 512 pairs, 2 per thread ----
    for (int p = tid; p < BT * JT; p += NT) {
        int bloc = p & (BT - 1);
        int j    = p >> 6;
        int bg   = b0 + bloc;
        int jc   = j0 + j;
        float gi = gbuf[bloc][j]      + bih[jc]          + bhh[jc];
        float gf = gbuf[bloc][8 + j]  + bih[Hd + jc]     + bhh[Hd + jc];
        float gg = gbuf[bloc][16 + j] + bih[2 * Hd + jc] + bhh[2 * Hd + jc];
        float go = gbuf[bloc][24 + j] + bih[3 * Hd + jc] + bhh[3 * Hd + jc];
        float cp = cprev[(size_t)bg * Hd + jc];
        float cn = sigm(gf) * cp + sigm(gi) * tanhf(gg);
        float hv = sigm(go) * tanhf(cn);
        if (mask) hv *= mask[(size_t)bg * Hd + jc];
        cnew[(size_t)bg * Hd + jc] = cn;
        hnew[(size_t)bg * Hd + jc] = hv;
        hbuf[bloc][j] = hv;
    }

    // ---- FC partial: out[b][m] += sum_{j in tile} h2[b][j] * Wfc[m][j] ----
    if (Wfc) {
        __syncthreads();
        if (tid < BT) {
            int bg = b0 + tid;
            #pragma unroll
            for (int m = 0; m < 3; ++m) {
                float s = 0.f;
                #pragma unroll
                for (int j = 0; j < JT; ++j) s += hbuf[tid][j] * Wfc[m * Hd + j0 + j];
                atomicAdd(&outp[bg * 3 + m], s);
            }
        }
    }
}

extern "C" void kernel_launch(void* const* d_in, const int* in_sizes, int n_in,
                              void* d_out, int out_size, void* d_ws, size_t ws_size,
                              hipStream_t stream)
{
    (void)in_sizes; (void)n_in; (void)out_size; (void)ws_size;
    const float* cond   = (const float*)d_in[0];
    const float* noise  = (const float*)d_in[1];
    const float* h_init = (const float*)d_in[2];
    const float* c_init = (const float*)d_in[3];
    const float* dmask  = (const float*)d_in[4];
    const float* Wih0   = (const float*)d_in[5];
    const float* Whh0   = (const float*)d_in[6];
    const float* bih0   = (const float*)d_in[7];
    const float* bhh0   = (const float*)d_in[8];
    const float* Wih1   = (const float*)d_in[9];
    const float* Whh1   = (const float*)d_in[10];
    const float* bih1   = (const float*)d_in[11];
    const float* bhh1   = (const float*)d_in[12];
    const float* Wih2   = (const float*)d_in[13];
    const float* Whh2   = (const float*)d_in[14];
    const float* bih2   = (const float*)d_in[15];
    const float* bhh2   = (const float*)d_in[16];
    const float* Wfc    = (const float*)d_in[17];
    const float* bfc    = (const float*)d_in[18];
    float* out = (float*)d_out;

    float* ws = (float*)d_ws;
    const size_t S = (size_t)Bb * Hd;
    float* h1a = ws;         float* h1b = ws + S;
    float* h2a = ws + 2 * S; float* h2b = ws + 3 * S;
    float* c1  = ws + 4 * S; float* c2  = ws + 5 * S;

    dim3 grid(Hd / JT, Bb / BT);  // (128, 2) = 256 WGs
    dim3 blk(NT);
    const int L = 256, Cd = 20, Nd = 30, Md = 3;

    // step 0: cell0 (cat(cond[0], noise), h_init, c_init) -> h1a (masked), c1
    lstm_cell_kernel<<<grid, blk, 0, stream>>>(
        h_init, Whh0, nullptr, nullptr,
        cond, Cd, noise, Nd, Wih0,
        bih0, bhh0, c_init, c1, dmask, h1a,
        nullptr, bfc, out, 1);
    // step 0: cell2 (h1a, h_init, c_init) -> h2a, c2; out[0] += h2a@Wfc.T
    lstm_cell_kernel<<<grid, blk, 0, stream>>>(
        h1a, Wih2, h_init, Whh2,
        nullptr, 0, nullptr, 0, nullptr,
        bih2, bhh2, c_init, c2, nullptr, h2a,
        Wfc, bfc, out, 0);

    const float* h1prev = h1a;
    const float* h2prev = h2a;
    for (int t = 1; t < L; ++t) {
        float* h1cur = (t & 1) ? h1b : h1a;
        float* h2cur = (t & 1) ? h2b : h2a;
        // cell1: cat(cond[t], out[t-1]) @ Wih1 + h1prev @ Whh1; dropout mask[t]
        lstm_cell_kernel<<<grid, blk, 0, stream>>>(
            h1prev, Whh1, nullptr, nullptr,
            cond + (size_t)t * Bb * Cd, Cd, out + (size_t)(t - 1) * Bb * Md, Md, Wih1,
            bih1, bhh1, c1, c1, dmask + (size_t)t * Bb * Hd, h1cur,
            nullptr, bfc, out + (size_t)t * Bb * Md, 1);
        // cell2: h1cur @ Wih2 + h2prev @ Whh2; FC accumulate into out[t]
        lstm_cell_kernel<<<grid, blk, 0, stream>>>(
            h1cur, Wih2, h2prev, Whh2,
            nullptr, 0, nullptr, 0, nullptr,
            bih2, bhh2, c2, c2, nullptr, h2cur,
            Wfc, bfc, out + (size_t)t * Bb * Md, 0);
        h1prev = h1cur;
        h2prev = h2cur;
    }
}

// Round 2
// 11519.627 us; speedup vs baseline: 4.1080x; 4.1080x over previous
//
#include <hip/hip_runtime.h>
#include <math.h>

// ---------------- problem constants ----------------
#define Bb   128
#define Hd   1024
#define Ld   256
#define Cd   20
#define Nd   30
#define Md   3

using bfrag  = __attribute__((ext_vector_type(8)))  short;  // 8 bf16
using f16v   = __attribute__((ext_vector_type(16))) float;  // 32x32 C/D

union Pack8 { bfrag v; unsigned short u[8]; };

__device__ __forceinline__ float sigm(float x) { return 1.0f / (1.0f + expf(-x)); }

__device__ __forceinline__ unsigned short bf_rne(float x) {
    unsigned u = __float_as_uint(x);
    unsigned r = (u + 0x7fffu + ((u >> 16) & 1u)) >> 16;
    return (unsigned short)r;
}
__device__ __forceinline__ float bf_f(unsigned short h) {
    return __uint_as_float(((unsigned)h) << 16);
}

#define MFMA(a,b,c) __builtin_amdgcn_mfma_f32_32x32x16_bf16((a),(b),(c),0,0,0)

// ---------------- split kernels (fp32 -> bf16 hi/lo) ----------------
__global__ void split_kernel(const float* __restrict__ src,
                             unsigned short* __restrict__ hi,
                             unsigned short* __restrict__ lo, int n)
{
    for (int i = blockIdx.x * blockDim.x + threadIdx.x; i < n; i += gridDim.x * blockDim.x) {
        float x = src[i];
        unsigned short h = bf_rne(x);
        hi[i] = h;
        lo[i] = bf_rne(x - bf_f(h));
    }
}

// pad K->Kp with zeros (row-major [rows][K] -> [rows][Kp])
__global__ void split_pad_kernel(const float* __restrict__ src,
                                 unsigned short* __restrict__ hi,
                                 unsigned short* __restrict__ lo,
                                 int rows, int K, int Kp)
{
    int n = rows * Kp;
    for (int i = blockIdx.x * blockDim.x + threadIdx.x; i < n; i += gridDim.x * blockDim.x) {
        int r = i / Kp, k = i - r * Kp;
        float x = (k < K) ? src[r * K + k] : 0.0f;
        unsigned short h = bf_rne(x);
        hi[i] = h;
        lo[i] = bf_rne(x - bf_f(h));
    }
}

// ---------------- MFMA fused LSTM-cell kernel ----------------
// MODE 1: cell1 — one big segment (K=1024) + small segment (cond(20)+out(3) via Wsm
//         padded to 32), dropout mask, init out slot to bfc.
// MODE 2: cell2 — two big segments (K=1024 each), FC epilogue (atomicAdd into out).
// Grid: 256 WGs x 512 threads. WG tile: 32 batch rows x (4 gates x 16 j-cols).
// K split across the 8 waves; per-wave frags read DIRECTLY from L2 (no LDS in loop).
template<int MODE>
__global__ __launch_bounds__(512, 2) void mfma_cell(
    const unsigned short* __restrict__ Ahi0, const unsigned short* __restrict__ Alo0,
    const unsigned short* __restrict__ Whi0, const unsigned short* __restrict__ Wlo0,
    const unsigned short* __restrict__ Ahi1, const unsigned short* __restrict__ Alo1,
    const unsigned short* __restrict__ Whi1, const unsigned short* __restrict__ Wlo1,
    const float* __restrict__ condt, const float* __restrict__ outprev,
    const unsigned short* __restrict__ Wsmhi, const unsigned short* __restrict__ Wsmlo,
    const float* __restrict__ bih, const float* __restrict__ bhh,
    const float* __restrict__ cprev, float* __restrict__ cnew,
    const float* __restrict__ maskt,
    unsigned short* __restrict__ Hhi, unsigned short* __restrict__ Hlo,
    const float* __restrict__ Wfc, const float* __restrict__ bfc,
    float* __restrict__ outp)
{
    __shared__ float part[8][32][65];   // 8 wave-partials, padded stride
    __shared__ float hbuf[32][16];

    const int bid  = blockIdx.x;
    // XCD swizzle: the 4 m-variants of a j-tile land on the same XCD (bid mod 8)
    const int mtile = (bid >> 3) & 3;
    const int jtile = (bid & 7) * 8 + (bid >> 5);
    const int j0 = jtile * 16;
    const int m0 = mtile * 32;

    const int tid  = threadIdx.x;
    const int wave = tid >> 6;
    const int lane = tid & 63;
    const int ml   = lane & 31;
    const int q    = lane >> 5;

    if (MODE == 1 && bid == 0) {
        for (int i = tid; i < Bb * Md; i += 512) outp[i] = bfc[i % Md];
    }

    // B rows for the two 32-wide N frags: nn = ml (+32)
    const int g0 = ml >> 4, jj0 = ml & 15;
    const size_t row0 = (size_t)(g0 * Hd + j0 + jj0);          // gates 0/1
    const size_t row1 = (size_t)((g0 + 2) * Hd + j0 + jj0);    // gates 2/3

    f16v C0, C1;
    #pragma unroll
    for (int r = 0; r < 16; ++r) { C0[r] = 0.0f; C1[r] = 0.0f; }

    // ---- big-K main loop: per-wave K range, frags straight from global/L2 ----
    constexpr int NIT = (MODE == 1) ? 8 : 16;
    const unsigned short *Ah, *Al, *Wh, *Wl;
    int kb;
    if (MODE == 1) { Ah = Ahi0; Al = Alo0; Wh = Whi0; Wl = Wlo0; kb = wave * 128; }
    else {
        if (wave < 4) { Ah = Ahi0; Al = Alo0; Wh = Whi0; Wl = Wlo0; }
        else          { Ah = Ahi1; Al = Alo1; Wh = Whi1; Wl = Wlo1; }
        kb = (wave & 3) * 256;
    }
    const size_t arow = (size_t)(m0 + ml) * Hd;
    #pragma unroll
    for (int it = 0; it < NIT; ++it) {
        const int k = kb + it * 16 + 8 * q;
        bfrag avh = *(const bfrag*)(Ah + arow + k);
        bfrag avl = *(const bfrag*)(Al + arow + k);
        bfrag b0h = *(const bfrag*)(Wh + row0 * Hd + k);
        bfrag b0l = *(const bfrag*)(Wl + row0 * Hd + k);
        bfrag b1h = *(const bfrag*)(Wh + row1 * Hd + k);
        bfrag b1l = *(const bfrag*)(Wl + row1 * Hd + k);
        C0 = MFMA(avh, b0h, C0);
        C1 = MFMA(avh, b1h, C1);
        C0 = MFMA(avl, b0h, C0);
        C1 = MFMA(avl, b1h, C1);
        C0 = MFMA(avh, b0l, C0);
        C1 = MFMA(avh, b1l, C1);
    }

    // ---- small segment (MODE1, wave 0 only): cat(cond[20], out[3]) pad->32 ----
    if (MODE == 1 && wave == 0) {
        const float* crow = condt + (m0 + ml) * Cd;
        const float* orow = outprev + (m0 + ml) * Md;
        float xv[2][8];
        #pragma unroll
        for (int j = 0; j < 8; ++j) { xv[0][j] = 0.f; xv[1][j] = 0.f; }
        if (q == 0) {
            #pragma unroll
            for (int j = 0; j < 8; ++j) xv[0][j] = crow[j];          // k 0..7
            xv[1][0] = crow[16]; xv[1][1] = crow[17];                 // k 16..19
            xv[1][2] = crow[18]; xv[1][3] = crow[19];
            xv[1][4] = orow[0];  xv[1][5] = orow[1];  xv[1][6] = orow[2]; // k 20..22
        } else {
            #pragma unroll
            for (int j = 0; j < 8; ++j) xv[0][j] = crow[8 + j];      // k 8..15
            // k 24..31 zero
        }
        #pragma unroll
        for (int ch = 0; ch < 2; ++ch) {
            Pack8 ah, al;
            #pragma unroll
            for (int j = 0; j < 8; ++j) {
                unsigned short h = bf_rne(xv[ch][j]);
                ah.u[j] = h;
                al.u[j] = bf_rne(xv[ch][j] - bf_f(h));
            }
            const int kk = ch * 16 + 8 * q;
            bfrag b0h = *(const bfrag*)(Wsmhi + row0 * 32 + kk);
            bfrag b0l = *(const bfrag*)(Wsmlo + row0 * 32 + kk);
            bfrag b1h = *(const bfrag*)(Wsmhi + row1 * 32 + kk);
            bfrag b1l = *(const bfrag*)(Wsmlo + row1 * 32 + kk);
            C0 = MFMA(ah.v, b0h, C0);
            C1 = MFMA(ah.v, b1h, C1);
            C0 = MFMA(al.v, b0h, C0);
            C1 = MFMA(al.v, b1h, C1);
            C0 = MFMA(ah.v, b0l, C0);
            C1 = MFMA(ah.v, b1l, C1);
        }
    }

    // ---- cross-wave reduce: write C frags to LDS ----
    #pragma unroll
    for (int r = 0; r < 16; ++r) {
        const int mrow = (r & 3) + 8 * (r >> 2) + 4 * q;
        part[wave][mrow][ml]      = C0[r];
        part[wave][mrow][32 + ml] = C1[r];
    }
    __syncthreads();

    // ---- reduction + LSTM elementwise: 512 threads, one (m, jj) each ----
    {
        const int m  = tid >> 4;
        const int jj = tid & 15;
        float g[4];
        #pragma unroll
        for (int gg = 0; gg < 4; ++gg) {
            float s = 0.0f;
            #pragma unroll
            for (int w = 0; w < 8; ++w) s += part[w][m][gg * 16 + jj];
            const int n = gg * Hd + j0 + jj;
            g[gg] = s + bih[n] + bhh[n];
        }
        const int b  = m0 + m;
        const int jc = j0 + jj;
        const size_t idx = (size_t)b * Hd + jc;
        float cp = cprev[idx];
        float cn = sigm(g[1]) * cp + sigm(g[0]) * tanhf(g[2]);
        float hv = sigm(g[3]) * tanhf(cn);
        if (MODE == 1) hv *= maskt[idx];
        cnew[idx] = cn;
        unsigned short hh = bf_rne(hv);
        Hhi[idx] = hh;
        Hlo[idx] = bf_rne(hv - bf_f(hh));
        if (MODE == 2) hbuf[m][jj] = hv;
    }

    // ---- FC epilogue (MODE2): out[b][m] += sum_j h2[b][j]*Wfc[m][j] ----
    if (MODE == 2) {
        __syncthreads();
        if (tid < 32) {
            const int b = m0 + tid;
            #pragma unroll
            for (int mm = 0; mm < Md; ++mm) {
                float s = 0.0f;
                #pragma unroll
                for (int jj = 0; jj < 16; ++jj) s += hbuf[tid][jj] * Wfc[mm * Hd + j0 + jj];
                atomicAdd(&outp[b * Md + mm], s);
            }
        }
    }
}

// ---------------- R0 fp32 VALU cell kernel (step 0 + ws fallback) ----------------
#define BT   64
#define JT   8
#define RT   32
#define KC   64
#define NT   256
#define NCHUNK 16
#define XSs  68
#define SMs  52
#define GBs  33

__global__ __launch_bounds__(NT) void lstm_cell_kernel(
    const float* __restrict__ Xbig0, const float* __restrict__ Wbig0,
    const float* __restrict__ Xbig1, const float* __restrict__ Wbig1,
    const float* __restrict__ Xsm0p, int K0,
    const float* __restrict__ Xsm1p, int K1,
    const float* __restrict__ Wsmall,
    const float* __restrict__ bih, const float* __restrict__ bhh,
    const float* __restrict__ cprev, float* __restrict__ cnew,
    const float* __restrict__ mask,
    float* __restrict__ hnew,
    const float* __restrict__ Wfc, const float* __restrict__ bfc,
    float* __restrict__ outp, int initOut)
{
    __shared__ float Xs[BT][XSs];
    __shared__ float Ws[RT][XSs];
    __shared__ float gbuf[BT][GBs];
    __shared__ float hbuf[BT][JT];
    __shared__ float Xsm[BT][SMs];
    __shared__ float Wsm[RT][SMs];

    const int tid = threadIdx.x;
    const int j0  = blockIdx.x * JT;
    const int b0  = blockIdx.y * BT;
    const int jp  = tid & 15;
    const int bq  = tid >> 4;

    auto GROW = [&](int r) { return ((r >> 3) * Hd + j0 + (r & 7)); };

    float acc[4][2];
    #pragma unroll
    for (int i = 0; i < 4; ++i) { acc[i][0] = 0.f; acc[i][1] = 0.f; }

    if (initOut && blockIdx.x == 0 && blockIdx.y == 0) {
        for (int i = tid; i < Bb * 3; i += NT) outp[i] = bfc[i % 3];
    }

    for (int seg = 0; seg < 2; ++seg) {
        const float* __restrict__ Xg = (seg == 0) ? Xbig0 : Xbig1;
        const float* __restrict__ Wg = (seg == 0) ? Wbig0 : Wbig1;
        if (Xg == nullptr) continue;

        float4 xr[4], wr[2];
        #pragma unroll
        for (int p = 0; p < 4; ++p) {
            int fi = p * NT + tid; int bloc = fi >> 4; int kq = fi & 15;
            xr[p] = *(const float4*)(Xg + (size_t)(b0 + bloc) * Hd + kq * 4);
        }
        #pragma unroll
        for (int p = 0; p < 2; ++p) {
            int fi = p * NT + tid; int r = fi >> 4; int kq = fi & 15;
            wr[p] = *(const float4*)(Wg + (size_t)GROW(r) * Hd + kq * 4);
        }
        #pragma unroll
        for (int p = 0; p < 4; ++p) { int fi = p * NT + tid; *(float4*)&Xs[fi >> 4][(fi & 15) * 4] = xr[p]; }
        #pragma unroll
        for (int p = 0; p < 2; ++p) { int fi = p * NT + tid; *(float4*)&Ws[fi >> 4][(fi & 15) * 4] = wr[p]; }
        __syncthreads();

        for (int kc = 0; kc < NCHUNK; ++kc) {
            const bool more = (kc + 1) < NCHUNK;
            if (more) {
                const int k0n = (kc + 1) * KC;
                #pragma unroll
                for (int p = 0; p < 4; ++p) {
                    int fi = p * NT + tid; int bloc = fi >> 4; int kq = fi & 15;
                    xr[p] = *(const float4*)(Xg + (size_t)(b0 + bloc) * Hd + k0n + kq * 4);
                }
                #pragma unroll
                for (int p = 0; p < 2; ++p) {
                    int fi = p * NT + tid; int r = fi >> 4; int kq = fi & 15;
                    wr[p] = *(const float4*)(Wg + (size_t)GROW(r) * Hd + k0n + kq * 4);
                }
            }
            #pragma unroll 4
            for (int kk = 0; kk < KC; kk += 4) {
                float4 w0 = *(const float4*)&Ws[jp][kk];
                float4 w1 = *(const float4*)&Ws[jp + 16][kk];
                #pragma unroll
                for (int bb = 0; bb < 4; ++bb) {
                    float4 xvv = *(const float4*)&Xs[bq + 16 * bb][kk];
                    acc[bb][0] += xvv.x * w0.x + xvv.y * w0.y + xvv.z * w0.z + xvv.w * w0.w;
                    acc[bb][1] += xvv.x * w1.x + xvv.y * w1.y + xvv.z * w1.z + xvv.w * w1.w;
                }
            }
            __syncthreads();
            if (more) {
                #pragma unroll
                for (int p = 0; p < 4; ++p) { int fi = p * NT + tid; *(float4*)&Xs[fi >> 4][(fi & 15) * 4] = xr[p]; }
                #pragma unroll
                for (int p = 0; p < 2; ++p) { int fi = p * NT + tid; *(float4*)&Ws[fi >> 4][(fi & 15) * 4] = wr[p]; }
                __syncthreads();
            }
        }
    }

    if (Wsmall) {
        const int Kt = K0 + K1;
        for (int i = tid; i < BT * Kt; i += NT) {
            int bloc = i / Kt, k = i % Kt;
            Xsm[bloc][k] = (k < K0) ? Xsm0p[(size_t)(b0 + bloc) * K0 + k]
                                    : Xsm1p[(size_t)(b0 + bloc) * K1 + (k - K0)];
        }
        for (int i = tid; i < RT * Kt; i += NT) {
            int r = i / Kt, k = i % Kt;
            Wsm[r][k] = Wsmall[(size_t)GROW(r) * Kt + k];
        }
        __syncthreads();
        for (int k = 0; k < Kt; ++k) {
            float w0 = Wsm[jp][k], w1 = Wsm[jp + 16][k];
            #pragma unroll
            for (int bb = 0; bb < 4; ++bb) {
                float xvv = Xsm[bq + 16 * bb][k];
                acc[bb][0] += xvv * w0;
                acc[bb][1] += xvv * w1;
            }
        }
    }

    __syncthreads();
    #pragma unroll
    for (int bb = 0; bb < 4; ++bb) {
        gbuf[bq + 16 * bb][jp]      = acc[bb][0];
        gbuf[bq + 16 * bb][jp + 16] = acc[bb][1];
    }
    __syncthreads();

    for (int p = tid; p < BT * JT; p += NT) {
        int bloc = p & (BT - 1);
        int j    = p >> 6;
        int bg   = b0 + bloc;
        int jc   = j0 + j;
        float gi = gbuf[bloc][j]      + bih[jc]          + bhh[jc];
        float gf = gbuf[bloc][8 + j]  + bih[Hd + jc]     + bhh[Hd + jc];
        float gg = gbuf[bloc][16 + j] + bih[2 * Hd + jc] + bhh[2 * Hd + jc];
        float go = gbuf[bloc][24 + j] + bih[3 * Hd + jc] + bhh[3 * Hd + jc];
        float cp = cprev[(size_t)bg * Hd + jc];
        float cn = sigm(gf) * cp + sigm(gi) * tanhf(gg);
        float hv = sigm(go) * tanhf(cn);
        if (mask) hv *= mask[(size_t)bg * Hd + jc];
        cnew[(size_t)bg * Hd + jc] = cn;
        hnew[(size_t)bg * Hd + jc] = hv;
        hbuf[bloc][j] = hv;
    }

    if (Wfc) {
        __syncthreads();
        if (tid < BT) {
            int bg = b0 + tid;
            #pragma unroll
            for (int m = 0; m < 3; ++m) {
                float s = 0.f;
                #pragma unroll
                for (int j = 0; j < JT; ++j) s += hbuf[tid][j] * Wfc[m * Hd + j0 + j];
                atomicAdd(&outp[bg * 3 + m], s);
            }
        }
    }
}

// ---------------- launch ----------------
extern "C" void kernel_launch(void* const* d_in, const int* in_sizes, int n_in,
                              void* d_out, int out_size, void* d_ws, size_t ws_size,
                              hipStream_t stream)
{
    (void)in_sizes; (void)n_in; (void)out_size;
    const float* cond   = (const float*)d_in[0];
    const float* noise  = (const float*)d_in[1];
    const float* h_init = (const float*)d_in[2];
    const float* c_init = (const float*)d_in[3];
    const float* dmask  = (const float*)d_in[4];
    const float* Wih0   = (const float*)d_in[5];
    const float* Whh0   = (const float*)d_in[6];
    const float* bih0   = (const float*)d_in[7];
    const float* bhh0   = (const float*)d_in[8];
    const float* Wih1   = (const float*)d_in[9];
    const float* Whh1   = (const float*)d_in[10];
    const float* bih1   = (const float*)d_in[11];
    const float* bhh1   = (const float*)d_in[12];
    const float* Wih2   = (const float*)d_in[13];
    const float* Whh2   = (const float*)d_in[14];
    const float* bih2   = (const float*)d_in[15];
    const float* bhh2   = (const float*)d_in[16];
    const float* Wfc    = (const float*)d_in[17];
    const float* bfc    = (const float*)d_in[18];
    float* out = (float*)d_out;

    char* wsb = (char*)d_ws;
    size_t off = 0;
    auto alloc = [&](size_t bytes) { size_t o = off; off += (bytes + 255) & ~(size_t)255; return o; };

    const size_t WBIG = (size_t)4 * Hd * Hd * 2;     // 4096*1024 bf16
    const size_t HB   = (size_t)Bb * Hd * 2;         // 128*1024 bf16
    const size_t HF   = (size_t)Bb * Hd * 4;         // 128*1024 fp32

    size_t o_w1h = alloc(WBIG), o_w1l = alloc(WBIG);          // Whh1
    size_t o_w2h = alloc(WBIG), o_w2l = alloc(WBIG);          // Wih2
    size_t o_w3h = alloc(WBIG), o_w3l = alloc(WBIG);          // Whh2
    size_t o_wsh = alloc((size_t)4 * Hd * 32 * 2);            // Wih1 padded hi
    size_t o_wsl = alloc((size_t)4 * Hd * 32 * 2);            // lo
    size_t o_h1h[2] = { alloc(HB), alloc(HB) };
    size_t o_h1l[2] = { alloc(HB), alloc(HB) };
    size_t o_h2h[2] = { alloc(HB), alloc(HB) };
    size_t o_h2l[2] = { alloc(HB), alloc(HB) };
    size_t o_c1 = alloc(HF), o_c2 = alloc(HF);
    size_t o_f1 = alloc(HF), o_f2 = alloc(HF);                // step-0 fp32 h
    const size_t needed = off;

    if (ws_size < needed) {
        // -------- fallback: full R0 fp32 path (correct on any ws >= 3 MB) --------
        float* ws = (float*)d_ws;
        const size_t S = (size_t)Bb * Hd;
        float* h1a = ws;         float* h1b = ws + S;
        float* h2a = ws + 2 * S; float* h2b = ws + 3 * S;
        float* c1  = ws + 4 * S; float* c2  = ws + 5 * S;
        dim3 grid(Hd / JT, Bb / BT);
        dim3 blk(NT);
        lstm_cell_kernel<<<grid, blk, 0, stream>>>(
            h_init, Whh0, nullptr, nullptr, cond, Cd, noise, Nd, Wih0,
            bih0, bhh0, c_init, c1, dmask, h1a, nullptr, bfc, out, 1);
        lstm_cell_kernel<<<grid, blk, 0, stream>>>(
            h1a, Wih2, h_init, Whh2, nullptr, 0, nullptr, 0, nullptr,
            bih2, bhh2, c_init, c2, nullptr, h2a, Wfc, bfc, out, 0);
        const float* h1prev = h1a; const float* h2prev = h2a;
        for (int t = 1; t < Ld; ++t) {
            float* h1cur = (t & 1) ? h1b : h1a;
            float* h2cur = (t & 1) ? h2b : h2a;
            lstm_cell_kernel<<<grid, blk, 0, stream>>>(
                h1prev, Whh1, nullptr, nullptr,
                cond + (size_t)t * Bb * Cd, Cd, out + (size_t)(t - 1) * Bb * Md, Md, Wih1,
                bih1, bhh1, c1, c1, dmask + (size_t)t * Bb * Hd, h1cur,
                nullptr, bfc, out + (size_t)t * Bb * Md, 1);
            lstm_cell_kernel<<<grid, blk, 0, stream>>>(
                h1cur, Wih2, h2prev, Whh2, nullptr, 0, nullptr, 0, nullptr,
                bih2, bhh2, c2, c2, nullptr, h2cur, Wfc, bfc, out + (size_t)t * Bb * Md, 0);
            h1prev = h1cur; h2prev = h2cur;
        }
        return;
    }

    // -------- MFMA path --------
    auto U16 = [&](size_t o) { return (unsigned short*)(wsb + o); };
    auto F32 = [&](size_t o) { return (float*)(wsb + o); };

    // 1) split weights to bf16 hi/lo (re-done every call; ws is re-poisoned)
    const int NW = 4 * Hd * Hd;
    split_kernel<<<2048, 256, 0, stream>>>(Whh1, U16(o_w1h), U16(o_w1l), NW);
    split_kernel<<<2048, 256, 0, stream>>>(Wih2, U16(o_w2h), U16(o_w2l), NW);
    split_kernel<<<2048, 256, 0, stream>>>(Whh2, U16(o_w3h), U16(o_w3l), NW);
    split_pad_kernel<<<512, 256, 0, stream>>>(Wih1, U16(o_wsh), U16(o_wsl), 4 * Hd, Cd + Md, 32);

    // 2) step 0 via the proven fp32 kernel
    {
        dim3 grid(Hd / JT, Bb / BT);
        dim3 blk(NT);
        lstm_cell_kernel<<<grid, blk, 0, stream>>>(
            h_init, Whh0, nullptr, nullptr, cond, Cd, noise, Nd, Wih0,
            bih0, bhh0, c_init, F32(o_c1), dmask, F32(o_f1), nullptr, bfc, out, 1);
        lstm_cell_kernel<<<grid, blk, 0, stream>>>(
            F32(o_f1), Wih2, h_init, Whh2, nullptr, 0, nullptr, 0, nullptr,
            bih2, bhh2, c_init, F32(o_c2), nullptr, F32(o_f2), Wfc, bfc, out, 0);
        split_kernel<<<256, 256, 0, stream>>>(F32(o_f1), U16(o_h1h[0]), U16(o_h1l[0]), Bb * Hd);
        split_kernel<<<256, 256, 0, stream>>>(F32(o_f2), U16(o_h2h[0]), U16(o_h2l[0]), Bb * Hd);
    }

    // 3) steps 1..255 via MFMA cells
    for (int t = 1; t < Ld; ++t) {
        const int cur = t & 1, prv = (t - 1) & 1;
        // cell1: h1_prev @ Whh1 (big) + cat(cond_t, out_{t-1}) @ Wih1 (small); mask
        mfma_cell<1><<<256, 512, 0, stream>>>(
            U16(o_h1h[prv]), U16(o_h1l[prv]), U16(o_w1h), U16(o_w1l),
            nullptr, nullptr, nullptr, nullptr,
            cond + (size_t)t * Bb * Cd, out + (size_t)(t - 1) * Bb * Md,
            U16(o_wsh), U16(o_wsl),
            bih1, bhh1, F32(o_c1), F32(o_c1),
            dmask + (size_t)t * Bb * Hd,
            U16(o_h1h[cur]), U16(o_h1l[cur]),
            nullptr, bfc, out + (size_t)t * Bb * Md);
        // cell2: h1_cur @ Wih2 + h2_prev @ Whh2; FC accumulate
        mfma_cell<2><<<256, 512, 0, stream>>>(
            U16(o_h1h[cur]), U16(o_h1l[cur]), U16(o_w2h), U16(o_w2l),
            U16(o_h2h[prv]), U16(o_h2l[prv]), U16(o_w3h), U16(o_w3l),
            nullptr, nullptr, nullptr, nullptr,
            bih2, bhh2, F32(o_c2), F32(o_c2),
            nullptr,
            U16(o_h2h[cur]), U16(o_h2l[cur]),
            Wfc, bfc, out + (size_t)t * Bb * Md);
    }
}

// Round 3
// 6450.533 us; speedup vs baseline: 7.3362x; 1.7858x over previous
//
#include <hip/hip_runtime.h>
#include <math.h>

// ---------------- problem constants ----------------
#define Bb   128
#define Hd   1024
#define Ld   256
#define Cd   20
#define Nd   30
#define Md   3

using bfrag = __attribute__((ext_vector_type(8)))  short;  // 8 bf16 (4 VGPRs)
using f16v  = __attribute__((ext_vector_type(16))) float;  // 32x32 C/D

union Pack8 { bfrag v; unsigned short u[8]; };

__device__ __forceinline__ float sigm(float x) { return 1.0f / (1.0f + expf(-x)); }

__device__ __forceinline__ unsigned short bf_rne(float x) {
    unsigned u = __float_as_uint(x);
    unsigned r = (u + 0x7fffu + ((u >> 16) & 1u)) >> 16;
    return (unsigned short)r;
}
__device__ __forceinline__ float bf_f(unsigned short h) {
    return __uint_as_float(((unsigned)h) << 16);
}

#define MFMA(a,b,c) __builtin_amdgcn_mfma_f32_32x32x16_bf16((a),(b),(c),0,0,0)

// async global->LDS, 16B per lane; LDS dest = wave-uniform base + lane*16
__device__ __forceinline__ void gld_lds16(const void* g, void* s) {
    __builtin_amdgcn_global_load_lds((const __attribute__((address_space(1))) void*)g,
                                     (__attribute__((address_space(3))) void*)s, 16, 0, 0);
}
// s_waitcnt imm: vmcnt[3:0] | expcnt<<4 (7=nowait) | lgkmcnt<<8 (15=nowait)
#define WAIT_VM(n) __builtin_amdgcn_s_waitcnt(0x0F70 | (n))
#define BARRIER()  __builtin_amdgcn_s_barrier()

// ---------------- preamble kernels ----------------
__global__ void cast_kernel(const float* __restrict__ src,
                            unsigned short* __restrict__ dst, int n)
{
    for (int i = blockIdx.x * blockDim.x + threadIdx.x; i < n; i += gridDim.x * blockDim.x)
        dst[i] = bf_rne(src[i]);
}

__global__ void cast_pad_kernel(const float* __restrict__ src,
                                unsigned short* __restrict__ dst,
                                int rows, int K, int Kp)
{
    int n = rows * Kp;
    for (int i = blockIdx.x * blockDim.x + threadIdx.x; i < n; i += gridDim.x * blockDim.x) {
        int r = i / Kp, k = i - r * Kp;
        dst[i] = bf_rne((k < K) ? src[r * K + k] : 0.0f);
    }
}

__global__ void split_kernel(const float* __restrict__ src,
                             unsigned short* __restrict__ hi,
                             unsigned short* __restrict__ lo, int n)
{
    for (int i = blockIdx.x * blockDim.x + threadIdx.x; i < n; i += gridDim.x * blockDim.x) {
        float x = src[i];
        unsigned short h = bf_rne(x);
        hi[i] = h;
        lo[i] = bf_rne(x - bf_f(h));
    }
}

// ---------------- MFMA fused LSTM-cell, LDS-staged double-buffered ----------------
// MODE 1: cell1 — K=1024 (h1prev @ Whh1) + small seg (cat(cond,out) @ Wih1 pad32);
//         dropout mask; init out slot to bfc. NC=8 chunks.
// MODE 2: cell2 — K=2048 virtual (h1 @ Wih2 then h2 @ Whh2); FC atomics. NC=16.
// Grid 256 WGs x 512 thr (8 waves). Tile M=32 x N=64 (4 gates x 16 j).
// Chunk BK=128: A hi/lo 16KB + W 16KB staged via global_load_lds, dbuf.
// k8-blocks XOR-swizzled by (row&15) to break the 256B-row-stride bank conflict
// (global source address is free-form; only the LDS dest order is rigid).
template<int MODE>
__global__ __launch_bounds__(512, 1) void mfma_cell(
    const unsigned short* __restrict__ Ahi0, const unsigned short* __restrict__ Alo0,
    const unsigned short* __restrict__ W0,
    const unsigned short* __restrict__ Ahi1, const unsigned short* __restrict__ Alo1,
    const unsigned short* __restrict__ W1,
    const float* __restrict__ condt, const float* __restrict__ outprev,
    const unsigned short* __restrict__ Wsm,
    const float* __restrict__ bih, const float* __restrict__ bhh,
    const float* __restrict__ cprev, float* __restrict__ cnew,
    const float* __restrict__ maskt,
    unsigned short* __restrict__ Hhi, unsigned short* __restrict__ Hlo,
    const float* __restrict__ Wfc, const float* __restrict__ bfc,
    float* __restrict__ outp)
{
    __shared__ unsigned short Abuf[2][2][32 * 128];  // [buf][hi/lo][m][k swizzled]
    __shared__ unsigned short Wbuf[2][64 * 128];     // [buf][n][k swizzled]
    __shared__ float part[8][32][65];
    __shared__ float hbuf[32][16];

    const int bid   = blockIdx.x;
    const int mtile = (bid >> 3) & 3;
    const int jtile = (bid & 7) * 8 + (bid >> 5);    // XCD-swizzled
    const int j0 = jtile * 16;
    const int m0 = mtile * 32;

    const int tid  = threadIdx.x;
    const int wave = tid >> 6;
    const int lane = tid & 63;
    const int ml   = lane & 31;
    const int q    = lane >> 5;

    if (MODE == 1 && bid == 0) {
        for (int i = tid; i < Bb * Md; i += 512) outp[i] = bfc[i % Md];
    }

    // N-frag rows: C0 cols = n in [0,32) (gates 0/1), C1 cols = n in [32,64) (gates 2/3)
    const int g0 = ml >> 4, jj0 = ml & 15;
    const size_t row0 = (size_t)(g0 * Hd + j0 + jj0);
    const size_t row1 = (size_t)((g0 + 2) * Hd + j0 + jj0);

    f16v C0, C1;
    #pragma unroll
    for (int r = 0; r < 16; ++r) { C0[r] = 0.0f; C1[r] = 0.0f; }

    constexpr int NC = (MODE == 1) ? 8 : 16;

    // stage chunk c into buf p (4 global_load_lds per wave)
    auto stage = [&](int c, int p) {
        const unsigned short *Ah, *Al, *Wg; int cb;
        if (MODE == 2 && c >= 8) { Ah = Ahi1; Al = Alo1; Wg = W1; cb = (c - 8) * 128; }
        else                     { Ah = Ahi0; Al = Alo0; Wg = W0; cb = c * 128; }
        {   // A hi + lo: 512 slots each, one per thread
            const int m = tid >> 4, bp = tid & 15, bs = bp ^ (m & 15);
            const size_t goff = (size_t)(m0 + m) * Hd + cb + bs * 8;
            gld_lds16(Ah + goff, &Abuf[p][0][wave * 512]);
            gld_lds16(Al + goff, &Abuf[p][1][wave * 512]);
        }
        #pragma unroll
        for (int r = 0; r < 2; ++r) {  // W: 1024 slots, 2 rounds
            const int f = r * 512 + tid;
            const int n = f >> 4, bp = f & 15, bs = bp ^ (n & 15);
            const size_t goff = (size_t)((n >> 4) * Hd + j0 + (n & 15)) * Hd + cb + bs * 8;
            gld_lds16(Wg + goff, &Wbuf[p][r * 4096 + wave * 512]);
        }
    };

    stage(0, 0);
    for (int c = 0; c < NC; ++c) {
        const int p = c & 1;
        if (c + 1 < NC) { stage(c + 1, p ^ 1); WAIT_VM(4); }
        else            { WAIT_VM(0); }
        BARRIER();
        // compute: this wave's k16 = wave*16 within the chunk; k8-block b = 2*wave+q
        {
            const int b = 2 * wave + q;
            const int soff = (b ^ (ml & 15)) << 3;
            bfrag ah  = *(const bfrag*)&Abuf[p][0][ml * 128 + soff];
            bfrag al  = *(const bfrag*)&Abuf[p][1][ml * 128 + soff];
            bfrag w0f = *(const bfrag*)&Wbuf[p][ml * 128 + soff];
            bfrag w1f = *(const bfrag*)&Wbuf[p][(ml + 32) * 128 + soff];
            C0 = MFMA(ah, w0f, C0);
            C1 = MFMA(ah, w1f, C1);
            C0 = MFMA(al, w0f, C0);
            C1 = MFMA(al, w1f, C1);
        }
        BARRIER();
    }

    // ---- small segment (MODE1, wave 0): cat(cond[20], out[3]) padded to K=32 ----
    if (MODE == 1 && wave == 0) {
        const float* crow = condt + (m0 + ml) * Cd;
        const float* orow = outprev + (m0 + ml) * Md;
        float xv[2][8];
        #pragma unroll
        for (int j = 0; j < 8; ++j) { xv[0][j] = 0.f; xv[1][j] = 0.f; }
        if (q == 0) {
            #pragma unroll
            for (int j = 0; j < 8; ++j) xv[0][j] = crow[j];               // k 0..7
            xv[1][0] = crow[16]; xv[1][1] = crow[17];                      // k 16..19
            xv[1][2] = crow[18]; xv[1][3] = crow[19];
            xv[1][4] = orow[0];  xv[1][5] = orow[1];  xv[1][6] = orow[2];  // k 20..22
        } else {
            #pragma unroll
            for (int j = 0; j < 8; ++j) xv[0][j] = crow[8 + j];           // k 8..15
        }
        #pragma unroll
        for (int ch = 0; ch < 2; ++ch) {
            Pack8 ah, al;
            #pragma unroll
            for (int j = 0; j < 8; ++j) {
                unsigned short h = bf_rne(xv[ch][j]);
                ah.u[j] = h;
                al.u[j] = bf_rne(xv[ch][j] - bf_f(h));
            }
            const int kk = ch * 16 + 8 * q;
            bfrag b0 = *(const bfrag*)(Wsm + row0 * 32 + kk);
            bfrag b1 = *(const bfrag*)(Wsm + row1 * 32 + kk);
            C0 = MFMA(ah.v, b0, C0);
            C1 = MFMA(ah.v, b1, C1);
            C0 = MFMA(al.v, b0, C0);
            C1 = MFMA(al.v, b1, C1);
        }
    }

    // ---- cross-wave reduce via LDS ----
    #pragma unroll
    for (int r = 0; r < 16; ++r) {
        const int mrow = (r & 3) + 8 * (r >> 2) + 4 * q;
        part[wave][mrow][ml]      = C0[r];
        part[wave][mrow][32 + ml] = C1[r];
    }
    __syncthreads();

    // ---- reduction + LSTM elementwise: one (m, jj) per thread ----
    {
        const int m  = tid >> 4;
        const int jj = tid & 15;
        float g[4];
        #pragma unroll
        for (int gg = 0; gg < 4; ++gg) {
            float s = 0.0f;
            #pragma unroll
            for (int w = 0; w < 8; ++w) s += part[w][m][gg * 16 + jj];
            const int n = gg * Hd + j0 + jj;
            g[gg] = s + bih[n] + bhh[n];
        }
        const int b  = m0 + m;
        const int jc = j0 + jj;
        const size_t idx = (size_t)b * Hd + jc;
        float cp = cprev[idx];
        float cn = sigm(g[1]) * cp + sigm(g[0]) * tanhf(g[2]);
        float hv = sigm(g[3]) * tanhf(cn);
        if (MODE == 1) hv *= maskt[idx];
        cnew[idx] = cn;
        unsigned short hh = bf_rne(hv);
        Hhi[idx] = hh;
        Hlo[idx] = bf_rne(hv - bf_f(hh));
        if (MODE == 2) hbuf[m][jj] = hv;
    }

    // ---- FC epilogue (MODE2): out[b][m] += sum_j h2[b][j]*Wfc[m][j] ----
    if (MODE == 2) {
        __syncthreads();
        if (tid < 32) {
            const int b = m0 + tid;
            #pragma unroll
            for (int mm = 0; mm < Md; ++mm) {
                float s = 0.0f;
                #pragma unroll
                for (int jj = 0; jj < 16; ++jj) s += hbuf[tid][jj] * Wfc[mm * Hd + j0 + jj];
                atomicAdd(&outp[b * Md + mm], s);
            }
        }
    }
}

// ---------------- R0 fp32 VALU cell kernel (step 0 + ws fallback) ----------------
#define BT   64
#define JT   8
#define RT   32
#define KC   64
#define NT   256
#define NCHUNK 16
#define XSs  68
#define SMs  52
#define GBs  33

__global__ __launch_bounds__(NT) void lstm_cell_kernel(
    const float* __restrict__ Xbig0, const float* __restrict__ Wbig0,
    const float* __restrict__ Xbig1, const float* __restrict__ Wbig1,
    const float* __restrict__ Xsm0p, int K0,
    const float* __restrict__ Xsm1p, int K1,
    const float* __restrict__ Wsmall,
    const float* __restrict__ bih, const float* __restrict__ bhh,
    const float* __restrict__ cprev, float* __restrict__ cnew,
    const float* __restrict__ mask,
    float* __restrict__ hnew,
    const float* __restrict__ Wfc, const float* __restrict__ bfc,
    float* __restrict__ outp, int initOut)
{
    __shared__ float Xs[BT][XSs];
    __shared__ float Ws[RT][XSs];
    __shared__ float gbuf[BT][GBs];
    __shared__ float hbuf[BT][JT];
    __shared__ float Xsm[BT][SMs];
    __shared__ float Wsm[RT][SMs];

    const int tid = threadIdx.x;
    const int j0  = blockIdx.x * JT;
    const int b0  = blockIdx.y * BT;
    const int jp  = tid & 15;
    const int bq  = tid >> 4;

    auto GROW = [&](int r) { return ((r >> 3) * Hd + j0 + (r & 7)); };

    float acc[4][2];
    #pragma unroll
    for (int i = 0; i < 4; ++i) { acc[i][0] = 0.f; acc[i][1] = 0.f; }

    if (initOut && blockIdx.x == 0 && blockIdx.y == 0) {
        for (int i = tid; i < Bb * 3; i += NT) outp[i] = bfc[i % 3];
    }

    for (int seg = 0; seg < 2; ++seg) {
        const float* __restrict__ Xg = (seg == 0) ? Xbig0 : Xbig1;
        const float* __restrict__ Wg = (seg == 0) ? Wbig0 : Wbig1;
        if (Xg == nullptr) continue;

        float4 xr[4], wr[2];
        #pragma unroll
        for (int p = 0; p < 4; ++p) {
            int fi = p * NT + tid; int bloc = fi >> 4; int kq = fi & 15;
            xr[p] = *(const float4*)(Xg + (size_t)(b0 + bloc) * Hd + kq * 4);
        }
        #pragma unroll
        for (int p = 0; p < 2; ++p) {
            int fi = p * NT + tid; int r = fi >> 4; int kq = fi & 15;
            wr[p] = *(const float4*)(Wg + (size_t)GROW(r) * Hd + kq * 4);
        }
        #pragma unroll
        for (int p = 0; p < 4; ++p) { int fi = p * NT + tid; *(float4*)&Xs[fi >> 4][(fi & 15) * 4] = xr[p]; }
        #pragma unroll
        for (int p = 0; p < 2; ++p) { int fi = p * NT + tid; *(float4*)&Ws[fi >> 4][(fi & 15) * 4] = wr[p]; }
        __syncthreads();

        for (int kc = 0; kc < NCHUNK; ++kc) {
            const bool more = (kc + 1) < NCHUNK;
            if (more) {
                const int k0n = (kc + 1) * KC;
                #pragma unroll
                for (int p = 0; p < 4; ++p) {
                    int fi = p * NT + tid; int bloc = fi >> 4; int kq = fi & 15;
                    xr[p] = *(const float4*)(Xg + (size_t)(b0 + bloc) * Hd + k0n + kq * 4);
                }
                #pragma unroll
                for (int p = 0; p < 2; ++p) {
                    int fi = p * NT + tid; int r = fi >> 4; int kq = fi & 15;
                    wr[p] = *(const float4*)(Wg + (size_t)GROW(r) * Hd + k0n + kq * 4);
                }
            }
            #pragma unroll 4
            for (int kk = 0; kk < KC; kk += 4) {
                float4 w0 = *(const float4*)&Ws[jp][kk];
                float4 w1 = *(const float4*)&Ws[jp + 16][kk];
                #pragma unroll
                for (int bb = 0; bb < 4; ++bb) {
                    float4 xvv = *(const float4*)&Xs[bq + 16 * bb][kk];
                    acc[bb][0] += xvv.x * w0.x + xvv.y * w0.y + xvv.z * w0.z + xvv.w * w0.w;
                    acc[bb][1] += xvv.x * w1.x + xvv.y * w1.y + xvv.z * w1.z + xvv.w * w1.w;
                }
            }
            __syncthreads();
            if (more) {
                #pragma unroll
                for (int p = 0; p < 4; ++p) { int fi = p * NT + tid; *(float4*)&Xs[fi >> 4][(fi & 15) * 4] = xr[p]; }
                #pragma unroll
                for (int p = 0; p < 2; ++p) { int fi = p * NT + tid; *(float4*)&Ws[fi >> 4][(fi & 15) * 4] = wr[p]; }
                __syncthreads();
            }
        }
    }

    if (Wsmall) {
        const int Kt = K0 + K1;
        for (int i = tid; i < BT * Kt; i += NT) {
            int bloc = i / Kt, k = i % Kt;
            Xsm[bloc][k] = (k < K0) ? Xsm0p[(size_t)(b0 + bloc) * K0 + k]
                                    : Xsm1p[(size_t)(b0 + bloc) * K1 + (k - K0)];
        }
        for (int i = tid; i < RT * Kt; i += NT) {
            int r = i / Kt, k = i % Kt;
            Wsm[r][k] = Wsmall[(size_t)GROW(r) * Kt + k];
        }
        __syncthreads();
        for (int k = 0; k < Kt; ++k) {
            float w0 = Wsm[jp][k], w1 = Wsm[jp + 16][k];
            #pragma unroll
            for (int bb = 0; bb < 4; ++bb) {
                float xvv = Xsm[bq + 16 * bb][k];
                acc[bb][0] += xvv * w0;
                acc[bb][1] += xvv * w1;
            }
        }
    }

    __syncthreads();
    #pragma unroll
    for (int bb = 0; bb < 4; ++bb) {
        gbuf[bq + 16 * bb][jp]      = acc[bb][0];
        gbuf[bq + 16 * bb][jp + 16] = acc[bb][1];
    }
    __syncthreads();

    for (int p = tid; p < BT * JT; p += NT) {
        int bloc = p & (BT - 1);
        int j    = p >> 6;
        int bg   = b0 + bloc;
        int jc   = j0 + j;
        float gi = gbuf[bloc][j]      + bih[jc]          + bhh[jc];
        float gf = gbuf[bloc][8 + j]  + bih[Hd + jc]     + bhh[Hd + jc];
        float gg = gbuf[bloc][16 + j] + bih[2 * Hd + jc] + bhh[2 * Hd + jc];
        float go = gbuf[bloc][24 + j] + bih[3 * Hd + jc] + bhh[3 * Hd + jc];
        float cp = cprev[(size_t)bg * Hd + jc];
        float cn = sigm(gf) * cp + sigm(gi) * tanhf(gg);
        float hv = sigm(go) * tanhf(cn);
        if (mask) hv *= mask[(size_t)bg * Hd + jc];
        cnew[(size_t)bg * Hd + jc] = cn;
        hnew[(size_t)bg * Hd + jc] = hv;
        hbuf[bloc][j] = hv;
    }

    if (Wfc) {
        __syncthreads();
        if (tid < BT) {
            int bg = b0 + tid;
            #pragma unroll
            for (int m = 0; m < 3; ++m) {
                float s = 0.f;
                #pragma unroll
                for (int j = 0; j < JT; ++j) s += hbuf[tid][j] * Wfc[m * Hd + j0 + j];
                atomicAdd(&outp[bg * 3 + m], s);
            }
        }
    }
}

// ---------------- launch ----------------
extern "C" void kernel_launch(void* const* d_in, const int* in_sizes, int n_in,
                              void* d_out, int out_size, void* d_ws, size_t ws_size,
                              hipStream_t stream)
{
    (void)in_sizes; (void)n_in; (void)out_size;
    const float* cond   = (const float*)d_in[0];
    const float* noise  = (const float*)d_in[1];
    const float* h_init = (const float*)d_in[2];
    const float* c_init = (const float*)d_in[3];
    const float* dmask  = (const float*)d_in[4];
    const float* Wih0   = (const float*)d_in[5];
    const float* Whh0   = (const float*)d_in[6];
    const float* bih0   = (const float*)d_in[7];
    const float* bhh0   = (const float*)d_in[8];
    const float* Wih1   = (const float*)d_in[9];
    const float* Whh1   = (const float*)d_in[10];
    const float* bih1   = (const float*)d_in[11];
    const float* bhh1   = (const float*)d_in[12];
    const float* Wih2   = (const float*)d_in[13];
    const float* Whh2   = (const float*)d_in[14];
    const float* bih2   = (const float*)d_in[15];
    const float* bhh2   = (const float*)d_in[16];
    const float* Wfc    = (const float*)d_in[17];
    const float* bfc    = (const float*)d_in[18];
    float* out = (float*)d_out;

    char* wsb = (char*)d_ws;
    size_t off = 0;
    auto alloc = [&](size_t bytes) { size_t o = off; off += (bytes + 255) & ~(size_t)255; return o; };

    const size_t WBIG = (size_t)4 * Hd * Hd * 2;     // 4096x1024 bf16
    const size_t HB   = (size_t)Bb * Hd * 2;         // bf16 h buffer
    const size_t HF   = (size_t)Bb * Hd * 4;         // fp32

    size_t o_w1 = alloc(WBIG);                        // Whh1 bf16
    size_t o_w2 = alloc(WBIG);                        // Wih2 bf16
    size_t o_w3 = alloc(WBIG);                        // Whh2 bf16
    size_t o_wsm = alloc((size_t)4 * Hd * 32 * 2);    // Wih1 padded bf16
    size_t o_h1h[2] = { alloc(HB), alloc(HB) };
    size_t o_h1l[2] = { alloc(HB), alloc(HB) };
    size_t o_h2h[2] = { alloc(HB), alloc(HB) };
    size_t o_h2l[2] = { alloc(HB), alloc(HB) };
    size_t o_c1 = alloc(HF), o_c2 = alloc(HF);
    size_t o_f1 = alloc(HF), o_f2 = alloc(HF);
    const size_t needed = off;

    if (ws_size < needed) {
        // -------- fallback: full R0 fp32 path --------
        float* ws = (float*)d_ws;
        const size_t S = (size_t)Bb * Hd;
        float* h1a = ws;         float* h1b = ws + S;
        float* h2a = ws + 2 * S; float* h2b = ws + 3 * S;
        float* c1  = ws + 4 * S; float* c2  = ws + 5 * S;
        dim3 grid(Hd / JT, Bb / BT);
        dim3 blk(NT);
        lstm_cell_kernel<<<grid, blk, 0, stream>>>(
            h_init, Whh0, nullptr, nullptr, cond, Cd, noise, Nd, Wih0,
            bih0, bhh0, c_init, c1, dmask, h1a, nullptr, bfc, out, 1);
        lstm_cell_kernel<<<grid, blk, 0, stream>>>(
            h1a, Wih2, h_init, Whh2, nullptr, 0, nullptr, 0, nullptr,
            bih2, bhh2, c_init, c2, nullptr, h2a, Wfc, bfc, out, 0);
        const float* h1prev = h1a; const float* h2prev = h2a;
        for (int t = 1; t < Ld; ++t) {
            float* h1cur = (t & 1) ? h1b : h1a;
            float* h2cur = (t & 1) ? h2b : h2a;
            lstm_cell_kernel<<<grid, blk, 0, stream>>>(
                h1prev, Whh1, nullptr, nullptr,
                cond + (size_t)t * Bb * Cd, Cd, out + (size_t)(t - 1) * Bb * Md, Md, Wih1,
                bih1, bhh1, c1, c1, dmask + (size_t)t * Bb * Hd, h1cur,
                nullptr, bfc, out + (size_t)t * Bb * Md, 1);
            lstm_cell_kernel<<<grid, blk, 0, stream>>>(
                h1cur, Wih2, h2prev, Whh2, nullptr, 0, nullptr, 0, nullptr,
                bih2, bhh2, c2, c2, nullptr, h2cur, Wfc, bfc, out + (size_t)t * Bb * Md, 0);
            h1prev = h1cur; h2prev = h2cur;
        }
        return;
    }

    auto U16 = [&](size_t o) { return (unsigned short*)(wsb + o); };
    auto F32 = [&](size_t o) { return (float*)(wsb + o); };

    // 1) weights -> bf16 (single precision level; activations carry hi/lo)
    const int NW = 4 * Hd * Hd;
    cast_kernel<<<2048, 256, 0, stream>>>(Whh1, U16(o_w1), NW);
    cast_kernel<<<2048, 256, 0, stream>>>(Wih2, U16(o_w2), NW);
    cast_kernel<<<2048, 256, 0, stream>>>(Whh2, U16(o_w3), NW);
    cast_pad_kernel<<<512, 256, 0, stream>>>(Wih1, U16(o_wsm), 4 * Hd, Cd + Md, 32);

    // 2) step 0 via the proven fp32 kernel
    {
        dim3 grid(Hd / JT, Bb / BT);
        dim3 blk(NT);
        lstm_cell_kernel<<<grid, blk, 0, stream>>>(
            h_init, Whh0, nullptr, nullptr, cond, Cd, noise, Nd, Wih0,
            bih0, bhh0, c_init, F32(o_c1), dmask, F32(o_f1), nullptr, bfc, out, 1);
        lstm_cell_kernel<<<grid, blk, 0, stream>>>(
            F32(o_f1), Wih2, h_init, Whh2, nullptr, 0, nullptr, 0, nullptr,
            bih2, bhh2, c_init, F32(o_c2), nullptr, F32(o_f2), Wfc, bfc, out, 0);
        split_kernel<<<256, 256, 0, stream>>>(F32(o_f1), U16(o_h1h[0]), U16(o_h1l[0]), Bb * Hd);
        split_kernel<<<256, 256, 0, stream>>>(F32(o_f2), U16(o_h2h[0]), U16(o_h2l[0]), Bb * Hd);
    }

    // 3) steps 1..255 via LDS-staged MFMA cells
    for (int t = 1; t < Ld; ++t) {
        const int cur = t & 1, prv = (t - 1) & 1;
        mfma_cell<1><<<256, 512, 0, stream>>>(
            U16(o_h1h[prv]), U16(o_h1l[prv]), U16(o_w1),
            nullptr, nullptr, nullptr,
            cond + (size_t)t * Bb * Cd, out + (size_t)(t - 1) * Bb * Md,
            U16(o_wsm),
            bih1, bhh1, F32(o_c1), F32(o_c1),
            dmask + (size_t)t * Bb * Hd,
            U16(o_h1h[cur]), U16(o_h1l[cur]),
            nullptr, bfc, out + (size_t)t * Bb * Md);
        mfma_cell<2><<<256, 512, 0, stream>>>(
            U16(o_h1h[cur]), U16(o_h1l[cur]), U16(o_w2),
            U16(o_h2h[prv]), U16(o_h2l[prv]), U16(o_w3),
            nullptr, nullptr, nullptr,
            bih2, bhh2, F32(o_c2), F32(o_c2),
            nullptr,
            U16(o_h2h[cur]), U16(o_h2l[cur]),
            Wfc, bfc, out + (size_t)t * Bb * Md);
    }
}